// Round 4
// baseline (31.148 us; speedup 1.0000x reference)
//
#include <hip/hip_runtime.h>
#include <math.h>

// RKN cell: B=4096, LOD=64, LSD=128, H=64, NB=15, NE=436 (band +-3)
#define O_PM   0
#define O_PCU  524288
#define O_PCL  786432
#define O_PCS  1048576
#define O_NM   1310720
#define O_NCU  1835008
#define O_NCL  2097152
#define O_NCS  2359296

// ws layout (u32 words):
//  WS_W1 [0,4096)     W1 bf16 pairs, [16 k8][64 j] x 4 u32  (LDS staging image)
//  WS_W2 [4096,6144)  W2 [8 k8][64 j] x 4
//  WS_W3 [6144,6656)  W3 [8 k8][16 j] x 4 (j=15 zero)
//  WS_BAS[6656,20608) basis bf16 k-pairs [m(4)][k2(8)][e(436)] (k=15 zero)
//  WS_SPL[20608,20736) softplus(ltn) f32 [128]
#define WS_W1   0
#define WS_W2   4096
#define WS_W3   6144
#define WS_BAS  6656
#define WS_SPL  20608
#define WS_TOT  20736

__device__ __forceinline__ float rlane(float v, int l) {
    return __uint_as_float(__builtin_amdgcn_readlane(__float_as_uint(v), l));
}
__device__ __forceinline__ unsigned pk2(float a, float b) {   // 2xf32 -> 2xbf16 (RNE)
    unsigned ua = __float_as_uint(a), ub = __float_as_uint(b);
    ua += 0x7fffu + ((ua >> 16) & 1u);
    ub += 0x7fffu + ((ub >> 16) & 1u);
    return (ua >> 16) | (ub & 0xffff0000u);
}
__device__ __forceinline__ float lo16(unsigned w) { return __uint_as_float(w << 16); }
__device__ __forceinline__ float hi16(unsigned w) { return __uint_as_float(w & 0xffff0000u); }
__device__ __forceinline__ unsigned short tobf(float a) {
    unsigned ua = __float_as_uint(a);
    ua += 0x7fffu + ((ua >> 16) & 1u);
    return (unsigned short)(ua >> 16);
}
__device__ __forceinline__ float frombf(unsigned short u) {
    return __uint_as_float(((unsigned)u) << 16);
}
__device__ __forceinline__ float frcp(float x) { return __builtin_amdgcn_rcpf(x); }
__device__ __forceinline__ float ftanh(float x) {
    float e = __expf(2.f * x);
    return 1.f - 2.f * frcp(e + 1.f);
}

// ---------------- prep: pack weights/basis to bf16 images in ws ----------------
__global__ __launch_bounds__(256)
void prep_kernel(const float* __restrict__ W1, const float* __restrict__ W2,
                 const float* __restrict__ W3,
                 const float* __restrict__ b11, const float* __restrict__ b12,
                 const float* __restrict__ b21, const float* __restrict__ b22,
                 const float* __restrict__ ltn, unsigned* __restrict__ ws)
{
    const int t0 = blockIdx.x * 256 + threadIdx.x;
    for (int t = t0; t < WS_TOT; t += 16384) {
        unsigned val = 0u;
        if (t < 4096) {
            const int c = t & 3, j = (t >> 2) & 63, k8 = t >> 8;
            const float* p = W1 + j * 128 + k8 * 8 + c * 2;
            val = pk2(p[0], p[1]);
        } else if (t < 6144) {
            const int q = t - 4096;
            const int c = q & 3, j = (q >> 2) & 63, k8 = q >> 8;
            const float* p = W2 + j * 64 + k8 * 8 + c * 2;
            val = pk2(p[0], p[1]);
        } else if (t < 6656) {
            const int q = t - 6144;
            const int c = q & 3, j = (q >> 2) & 15, k8 = q >> 6;
            if (j < 15) { const float* p = W3 + j * 64 + k8 * 8 + c * 2; val = pk2(p[0], p[1]); }
        } else if (t < 20608) {
            const int q = t - 6656;
            const int e = q % 436, kk = q / 436;       // kk = m*8+k2
            const int m = kk >> 3, k2 = kk & 7;
            const float* bp = (m == 0) ? b11 : (m == 1) ? b12 : (m == 2) ? b21 : b22;
            const float lo = bp[(2 * k2) * 436 + e];
            const float hi = (2 * k2 + 1 < 15) ? bp[(2 * k2 + 1) * 436 + e] : 0.f;
            val = pk2(lo, hi);
        } else {
            const int q = t - 20608;
            val = __float_as_uint(logf(expf(ltn[q]) + 1.f));
        }
        ws[t] = val;
    }
}

// ---------------- main: 512 blocks x 512 threads, 8 rows/block ----------------
// LDS (u32 words), 9664 = 38656 B:
//  [0,6976)  weights image (1664 uint4)  UNION  tmv bf16 [32 mr][436]
//  [6976,8000) pm_s [8][128] f32
//  [8000,8512) pcu_s [8][64]; [8512,9024) pcl_s; [9024,9536) pcs_s
//  [9536,9664) coef_s [8][16] f32
__global__ __launch_bounds__(512, 4)
void rkn_kernel(const float* __restrict__ prior_mean,
                const float* __restrict__ cov_u,
                const float* __restrict__ cov_l,
                const float* __restrict__ cov_s,
                const float* __restrict__ obs,
                const float* __restrict__ obs_var,
                const float* __restrict__ b1,
                const float* __restrict__ b2,
                const float* __restrict__ b3,
                const unsigned* __restrict__ ws,
                float* __restrict__ out)
{
    __shared__ __align__(16) unsigned smem[9664];
    uint4* lds4 = (uint4*)smem;
    uint4* W1v  = (uint4*)smem;              // [16 k8][64 j]
    uint4* W2v  = (uint4*)(smem + 4096);     // [8 k8][64 j]
    uint4* W3v  = (uint4*)(smem + 6144);     // [8 k8][16 j]
    unsigned short* tmv = (unsigned short*)smem;   // [32][436] bf16 (union)
    float* pm_s   = (float*)(smem + 6976);
    float* pcu_s  = (float*)(smem + 8000);
    float* pcl_s  = (float*)(smem + 8512);
    float* pcs_s  = (float*)(smem + 9024);
    float* coef_s = (float*)(smem + 9536);

    const int tid  = threadIdx.x;
    const int wid  = tid >> 6;          // wave = row within block
    const int lane = tid & 63;
    const int row  = blockIdx.x * 8 + wid;
    const int jj   = lane & 15;

    // ---- issue per-row input loads first (HBM latency under staging) ----
    const float cu   = cov_u[row * 64 + lane];
    const float cl   = cov_l[row * 64 + lane];
    const float cs   = cov_s[row * 64 + lane];
    const float ob   = obs[row * 64 + lane];
    const float ov   = obs_var[row * 64 + lane];
    const float pmu0 = prior_mean[row * 128 + lane];
    const float pml0 = prior_mean[row * 128 + 64 + lane];
    const float bias1 = b1[lane];
    const float bias2 = b2[lane];
    const float bias3 = (jj < 15) ? b3[jj] : 0.f;

    // ---- stage weight image: pure uint4 copy (1664 uint4s) ----
    const uint4* ws4 = (const uint4*)ws;
#pragma unroll
    for (int it = 0; it < 4; ++it) {
        const int i = tid + it * 512;
        if (i < 1664) lds4[i] = ws4[i];
    }

    // ---- bulk basis prefetch: all 32 k-pair words for this thread's e ----
    const int e = (tid < 436) ? tid : 435;
    unsigned bas[32];
#pragma unroll
    for (int kk = 0; kk < 32; ++kk)
        bas[kk] = ws[WS_BAS + kk * 436 + e];

    // softplus(trans noise) from prep
    const float tcu = __uint_as_float(ws[WS_SPL + lane]);
    const float tcl = __uint_as_float(ws[WS_SPL + 64 + lane]);

    // ---- phase 1: Kalman update ----
    const float inv = frcp(cu + ov);
    const float qu  = cu * inv;
    const float ql  = cs * inv;
    const float res = ob - pmu0;
    const float pmu = pmu0 + qu * res;
    const float pml = pml0 + ql * res;
    const float cf  = 1.f - qu;
    const float pcu = cf * cu;
    const float pcl = cl - ql * cs;
    const float pcs = cf * cs;

    out[O_PM  + row * 128 + lane]      = pmu;
    out[O_PM  + row * 128 + 64 + lane] = pml;
    out[O_PCU + row * 64 + lane] = pcu;
    out[O_PCL + row * 64 + lane] = pcl;
    out[O_PCS + row * 64 + lane] = pcs;

    pm_s [wid * 128 + lane]      = pmu;
    pm_s [wid * 128 + 64 + lane] = pml;
    pcu_s[wid * 64 + lane] = pcu;
    pcl_s[wid * 64 + lane] = pcl;
    pcs_s[wid * 64 + lane] = pcs;

    __syncthreads();   // weights staged + row state visible

    // ---- phase 2: MLP (bf16x8 weight reads, readlane activation b'cast) ----
    float ac0 = bias1, ac1 = 0.f, ac2 = 0.f, ac3 = 0.f;
#pragma unroll
    for (int k8 = 0; k8 < 16; ++k8) {
        const uint4 wv = W1v[k8 * 64 + lane];
        const float src = (k8 < 8) ? pmu : pml;
        const int bl = (k8 & 7) * 8;
        ac0 += lo16(wv.x) * rlane(src, bl + 0);
        ac1 += hi16(wv.x) * rlane(src, bl + 1);
        ac2 += lo16(wv.y) * rlane(src, bl + 2);
        ac3 += hi16(wv.y) * rlane(src, bl + 3);
        ac0 += lo16(wv.z) * rlane(src, bl + 4);
        ac1 += hi16(wv.z) * rlane(src, bl + 5);
        ac2 += lo16(wv.w) * rlane(src, bl + 6);
        ac3 += hi16(wv.w) * rlane(src, bl + 7);
    }
    const float h1v = ftanh((ac0 + ac1) + (ac2 + ac3));

    ac0 = bias2; ac1 = 0.f; ac2 = 0.f; ac3 = 0.f;
#pragma unroll
    for (int k8 = 0; k8 < 8; ++k8) {
        const uint4 wv = W2v[k8 * 64 + lane];
        const int bl = k8 * 8;
        ac0 += lo16(wv.x) * rlane(h1v, bl + 0);
        ac1 += hi16(wv.x) * rlane(h1v, bl + 1);
        ac2 += lo16(wv.y) * rlane(h1v, bl + 2);
        ac3 += hi16(wv.y) * rlane(h1v, bl + 3);
        ac0 += lo16(wv.z) * rlane(h1v, bl + 4);
        ac1 += hi16(wv.z) * rlane(h1v, bl + 5);
        ac2 += lo16(wv.w) * rlane(h1v, bl + 6);
        ac3 += hi16(wv.w) * rlane(h1v, bl + 7);
    }
    const float h2v = ftanh((ac0 + ac1) + (ac2 + ac3));

    ac0 = bias3; ac1 = 0.f; ac2 = 0.f; ac3 = 0.f;
#pragma unroll
    for (int k8 = 0; k8 < 8; ++k8) {
        const uint4 wv = W3v[k8 * 16 + jj];
        const int bl = k8 * 8;
        ac0 += lo16(wv.x) * rlane(h2v, bl + 0);
        ac1 += hi16(wv.x) * rlane(h2v, bl + 1);
        ac2 += lo16(wv.y) * rlane(h2v, bl + 2);
        ac3 += hi16(wv.y) * rlane(h2v, bl + 3);
        ac0 += lo16(wv.z) * rlane(h2v, bl + 4);
        ac1 += hi16(wv.z) * rlane(h2v, bl + 5);
        ac2 += lo16(wv.w) * rlane(h2v, bl + 6);
        ac3 += hi16(wv.w) * rlane(h2v, bl + 7);
    }
    const float l3 = (ac0 + ac1) + (ac2 + ac3);   // logit jj lives in lane jj

    // ---- in-wave softmax (logit k in lane k, k<15) ----
    {
        float mx = rlane(l3, 0);
#pragma unroll
        for (int k = 1; k < 15; ++k) mx = fmaxf(mx, rlane(l3, k));
        const float ex = __expf(l3 - mx);
        float s = rlane(ex, 0);
#pragma unroll
        for (int k = 1; k < 15; ++k) s += rlane(ex, k);
        const float cval = ex * frcp(s);
        if (lane < 16) coef_s[wid * 16 + lane] = (lane < 15) ? cval : 0.f;
    }

    __syncthreads();   // coeffs visible; weight region now dead -> tmv reuse

    // ---- phase 3: tm[m][r][e] = sum_k coeff[r][k]*basis_m[k][e] (reg basis) ----
    {
        const float cv0 = coef_s[lane];        // r=0..3 (r=lane>>4, k=lane&15)
        const float cv1 = coef_s[64 + lane];   // r=4..7
        float acc3[4][8];
#pragma unroll
        for (int m = 0; m < 4; ++m)
#pragma unroll
            for (int r = 0; r < 8; ++r) acc3[m][r] = 0.f;

#pragma unroll
        for (int k2 = 0; k2 < 8; ++k2) {
            float c0[8], c1[8];
#pragma unroll
            for (int r = 0; r < 4; ++r) {
                c0[r]     = rlane(cv0, r * 16 + 2 * k2);
                c1[r]     = rlane(cv0, r * 16 + 2 * k2 + 1);
                c0[4 + r] = rlane(cv1, r * 16 + 2 * k2);
                c1[4 + r] = rlane(cv1, r * 16 + 2 * k2 + 1);
            }
#pragma unroll
            for (int m = 0; m < 4; ++m) {
                const unsigned bv = bas[m * 8 + k2];
                const float b0 = lo16(bv), b1 = hi16(bv);
#pragma unroll
                for (int r = 0; r < 8; ++r)
                    acc3[m][r] += c0[r] * b0 + c1[r] * b1;
            }
        }
        if (tid < 436) {
#pragma unroll
            for (int m = 0; m < 4; ++m)
#pragma unroll
                for (int r = 0; r < 8; ++r)
                    tmv[(m * 8 + r) * 436 + tid] = tobf(acc3[m][r]);
        }
    }

    __syncthreads();   // tm visible

    // ---- phase 4: banded mat-vec combos (wave=row r, lane i=output dim) ----
    {
        const int i   = lane;
        const int jlo = (i - 3 > 0) ? (i - 3) : 0;
        const int ne  = ((i + 3 < 63) ? (i + 3) : 63) - jlo + 1;
        const int base = (i < 4)  ? (i * (i + 7)) / 2
                       : (i <= 61) ? (7 * i - 6)
                       : (i == 62) ? 427 : 432;

        float nmu = 0.f, nml = 0.f, ncu = 0.f, ncl = 0.f, ncs = 0.f;
#pragma unroll
        for (int d = 0; d < 7; ++d) {
            if (d < ne) {
                const int j  = jlo + d;
                const int eI = base + d;
                float t11 = frombf(tmv[(0 * 8 + wid) * 436 + eI]);
                float t12 = frombf(tmv[(1 * 8 + wid) * 436 + eI]);
                float t21 = frombf(tmv[(2 * 8 + wid) * 436 + eI]);
                float t22 = frombf(tmv[(3 * 8 + wid) * 436 + eI]);
                if (j == i) { t11 += 1.f; t22 += 1.f; }
                const float mu  = pm_s[wid * 128 + j];
                const float ml  = pm_s[wid * 128 + 64 + j];
                const float vcu = pcu_s[wid * 64 + j];
                const float vcl = pcl_s[wid * 64 + j];
                const float vcs = pcs_s[wid * 64 + j];
                nmu += t11 * mu + t12 * ml;
                nml += t21 * mu + t22 * ml;
                ncu += t11 * t11 * vcu + 2.f * t11 * t12 * vcs + t12 * t12 * vcl;
                ncl += t21 * t21 * vcu + 2.f * t21 * t22 * vcs + t22 * t22 * vcl;
                ncs += t21 * t11 * vcu + (t22 * t11 + t21 * t12) * vcs + t22 * t12 * vcl;
            }
        }
        out[O_NM  + row * 128 + i]      = nmu;
        out[O_NM  + row * 128 + 64 + i] = nml;
        out[O_NCU + row * 64 + i] = ncu + tcu;
        out[O_NCL + row * 64 + i] = ncl + tcl;
        out[O_NCS + row * 64 + i] = ncs;
    }
}

extern "C" void kernel_launch(void* const* d_in, const int* in_sizes, int n_in,
                              void* d_out, int out_size, void* d_ws, size_t ws_size,
                              hipStream_t stream) {
    unsigned* ws = (unsigned*)d_ws;
    prep_kernel<<<dim3(64), dim3(256), 0, stream>>>(
        (const float*)d_in[6],  // W1
        (const float*)d_in[8],  // W2
        (const float*)d_in[10], // W3
        (const float*)d_in[12], // tm11_basis
        (const float*)d_in[13], // tm12_basis
        (const float*)d_in[14], // tm21_basis
        (const float*)d_in[15], // tm22_basis
        (const float*)d_in[16], // log_trans_noise
        ws);
    rkn_kernel<<<dim3(512), dim3(512), 0, stream>>>(
        (const float*)d_in[0],  // prior_mean
        (const float*)d_in[1],  // cov_u
        (const float*)d_in[2],  // cov_l
        (const float*)d_in[3],  // cov_s
        (const float*)d_in[4],  // obs
        (const float*)d_in[5],  // obs_var
        (const float*)d_in[7],  // b1
        (const float*)d_in[9],  // b2
        (const float*)d_in[11], // b3
        ws,
        (float*)d_out);
}

// Round 5
// 27.225 us; speedup vs baseline: 1.1441x; 1.1441x over previous
//
#include <hip/hip_runtime.h>
#include <math.h>

// RKN cell: B=4096, LOD=64, LSD=128, H=64, NB=15, NE=436 (band +-3)
#define O_PM   0
#define O_PCU  524288
#define O_PCL  786432
#define O_PCS  1048576
#define O_NM   1310720
#define O_NCU  1835008
#define O_NCL  2097152
#define O_NCS  2359296

__device__ __forceinline__ float rlane(float v, int l) {
    return __uint_as_float(__builtin_amdgcn_readlane(__float_as_uint(v), l));
}
__device__ __forceinline__ unsigned pk2(float a, float b) {   // 2xf32 -> 2xbf16 (RNE)
    unsigned ua = __float_as_uint(a), ub = __float_as_uint(b);
    ua += 0x7fffu + ((ua >> 16) & 1u);
    ub += 0x7fffu + ((ub >> 16) & 1u);
    return (ua >> 16) | (ub & 0xffff0000u);
}
__device__ __forceinline__ float lo16(unsigned w) { return __uint_as_float(w << 16); }
__device__ __forceinline__ float hi16(unsigned w) { return __uint_as_float(w & 0xffff0000u); }
__device__ __forceinline__ unsigned short tobf(float a) {
    unsigned ua = __float_as_uint(a);
    ua += 0x7fffu + ((ua >> 16) & 1u);
    return (unsigned short)(ua >> 16);
}
__device__ __forceinline__ float frombf(unsigned short u) {
    return __uint_as_float(((unsigned)u) << 16);
}
__device__ __forceinline__ float frcp(float x) { return __builtin_amdgcn_rcpf(x); }
__device__ __forceinline__ float ftanh(float x) {
    float e = __expf(2.f * x);
    return 1.f - 2.f * frcp(e + 1.f);
}

// 512 threads, 8 rows/block, 512 blocks. launch_bounds(512,4):
//   4 waves/SIMD -> 2 blocks/CU resident, VGPR budget 128 (NO spills; R2-R4
//   ran at a 64-102 cap and spilled ~75MB to scratch -> the real bottleneck).
// LDS (u32 words), 9664 = 38656 B (2 blocks/CU = 77 KB < 160):
//  [0,6976)  weights bf16 image: W1v [16k8][64j]u4 | W2v [8][64] | W3v [8][16]
//            UNION tmv bf16 [32 mr][436]
//  [6976,8000) pm_s [8][128] f32
//  [8000,8512) pcu_s; [8512,9024) pcl_s; [9024,9536) pcs_s   [8][64] each
//  [9536,9664) coef_s [8][16]
__global__ __launch_bounds__(512, 4)
void rkn_kernel(const float* __restrict__ prior_mean,
                const float* __restrict__ cov_u,
                const float* __restrict__ cov_l,
                const float* __restrict__ cov_s,
                const float* __restrict__ obs,
                const float* __restrict__ obs_var,
                const float* __restrict__ W1,
                const float* __restrict__ b1,
                const float* __restrict__ W2,
                const float* __restrict__ b2,
                const float* __restrict__ W3,
                const float* __restrict__ b3,
                const float* __restrict__ tm11b,
                const float* __restrict__ tm12b,
                const float* __restrict__ tm21b,
                const float* __restrict__ tm22b,
                const float* __restrict__ ltn,
                float* __restrict__ out)
{
    __shared__ __align__(16) unsigned smem[9664];
    uint4* lds4 = (uint4*)smem;
    uint4* W1v  = (uint4*)smem;              // [16 k8][64 j]
    uint4* W2v  = (uint4*)(smem + 4096);     // [8 k8][64 j]
    uint4* W3v  = (uint4*)(smem + 6144);     // [8 k8][16 j]
    unsigned short* tmv = (unsigned short*)smem;   // [32][436] bf16 (union)
    float* pm_s   = (float*)(smem + 6976);
    float* pcu_s  = (float*)(smem + 8000);
    float* pcl_s  = (float*)(smem + 8512);
    float* pcs_s  = (float*)(smem + 9024);
    float* coef_s = (float*)(smem + 9536);

    const int tid  = threadIdx.x;
    const int wid  = tid >> 6;          // wave = row within block
    const int lane = tid & 63;
    const int row  = blockIdx.x * 8 + wid;
    const int jj   = lane & 15;

    // ---- per-row input loads (coalesced; latency hidden under staging) ----
    const float cu   = cov_u[row * 64 + lane];
    const float cl   = cov_l[row * 64 + lane];
    const float cs   = cov_s[row * 64 + lane];
    const float ob   = obs[row * 64 + lane];
    const float ov   = obs_var[row * 64 + lane];
    const float pmu0 = prior_mean[row * 128 + lane];
    const float pml0 = prior_mean[row * 128 + 64 + lane];
    const float bias1 = b1[lane];
    const float bias2 = b2[lane];
    const float bias3 = (jj < 15) ? b3[jj] : 0.f;

    // ---- basis -> registers (60 f32), one e per thread; pure VALU phase 3 ----
    const int e = (tid < 436) ? tid : 435;
    float basf[60];
#pragma unroll
    for (int k = 0; k < 15; ++k) {
        basf[k]      = tm11b[k * 436 + e];
        basf[15 + k] = tm12b[k * 436 + e];
        basf[30 + k] = tm21b[k * 436 + e];
        basf[45 + k] = tm22b[k * 436 + e];
    }

    // ---- stage weight image: bf16-pack inline (1664 uint4) ----
#pragma unroll
    for (int it = 0; it < 4; ++it) {
        const int idx = tid + it * 512;
        if (idx < 1664) {
            uint4 v = make_uint4(0u, 0u, 0u, 0u);
            if (idx < 1024) {                 // W1: k8=idx>>6, j=idx&63
                const int j = idx & 63, k8 = idx >> 6;
                const float4* p = (const float4*)(W1 + j * 128 + k8 * 8);
                const float4 a = p[0], b = p[1];
                v = make_uint4(pk2(a.x, a.y), pk2(a.z, a.w), pk2(b.x, b.y), pk2(b.z, b.w));
            } else if (idx < 1536) {          // W2
                const int q = idx - 1024;
                const int j = q & 63, k8 = q >> 6;
                const float4* p = (const float4*)(W2 + j * 64 + k8 * 8);
                const float4 a = p[0], b = p[1];
                v = make_uint4(pk2(a.x, a.y), pk2(a.z, a.w), pk2(b.x, b.y), pk2(b.z, b.w));
            } else {                          // W3 (j=15 stays zero)
                const int q = idx - 1536;
                const int j = q & 15, k8 = q >> 4;
                if (j < 15) {
                    const float4* p = (const float4*)(W3 + j * 64 + k8 * 8);
                    const float4 a = p[0], b = p[1];
                    v = make_uint4(pk2(a.x, a.y), pk2(a.z, a.w), pk2(b.x, b.y), pk2(b.z, b.w));
                }
            }
            lds4[idx] = v;
        }
    }

    // softplus(trans noise), inline (128 distinct values, 2 exp+2 log/thread)
    const float tcu = logf(expf(ltn[lane]) + 1.f);
    const float tcl = logf(expf(ltn[64 + lane]) + 1.f);

    // ---- phase 1: Kalman update ----
    const float inv = frcp(cu + ov);
    const float qu  = cu * inv;
    const float ql  = cs * inv;
    const float res = ob - pmu0;
    const float pmu = pmu0 + qu * res;
    const float pml = pml0 + ql * res;
    const float cf  = 1.f - qu;
    const float pcu = cf * cu;
    const float pcl = cl - ql * cs;
    const float pcs = cf * cs;

    out[O_PM  + row * 128 + lane]      = pmu;
    out[O_PM  + row * 128 + 64 + lane] = pml;
    out[O_PCU + row * 64 + lane] = pcu;
    out[O_PCL + row * 64 + lane] = pcl;
    out[O_PCS + row * 64 + lane] = pcs;

    pm_s [wid * 128 + lane]      = pmu;
    pm_s [wid * 128 + 64 + lane] = pml;
    pcu_s[wid * 64 + lane] = pcu;
    pcl_s[wid * 64 + lane] = pcl;
    pcs_s[wid * 64 + lane] = pcs;

    __syncthreads();   // weights staged + row state visible

    // ---- phase 2: MLP (bf16x8 weight reads, readlane activation b'cast) ----
    float ac0 = bias1, ac1 = 0.f, ac2 = 0.f, ac3 = 0.f;
#pragma unroll
    for (int k8 = 0; k8 < 16; ++k8) {
        const uint4 wv = W1v[k8 * 64 + lane];
        const float src = (k8 < 8) ? pmu : pml;
        const int bl = (k8 & 7) * 8;
        ac0 += lo16(wv.x) * rlane(src, bl + 0);
        ac1 += hi16(wv.x) * rlane(src, bl + 1);
        ac2 += lo16(wv.y) * rlane(src, bl + 2);
        ac3 += hi16(wv.y) * rlane(src, bl + 3);
        ac0 += lo16(wv.z) * rlane(src, bl + 4);
        ac1 += hi16(wv.z) * rlane(src, bl + 5);
        ac2 += lo16(wv.w) * rlane(src, bl + 6);
        ac3 += hi16(wv.w) * rlane(src, bl + 7);
    }
    const float h1v = ftanh((ac0 + ac1) + (ac2 + ac3));

    ac0 = bias2; ac1 = 0.f; ac2 = 0.f; ac3 = 0.f;
#pragma unroll
    for (int k8 = 0; k8 < 8; ++k8) {
        const uint4 wv = W2v[k8 * 64 + lane];
        const int bl = k8 * 8;
        ac0 += lo16(wv.x) * rlane(h1v, bl + 0);
        ac1 += hi16(wv.x) * rlane(h1v, bl + 1);
        ac2 += lo16(wv.y) * rlane(h1v, bl + 2);
        ac3 += hi16(wv.y) * rlane(h1v, bl + 3);
        ac0 += lo16(wv.z) * rlane(h1v, bl + 4);
        ac1 += hi16(wv.z) * rlane(h1v, bl + 5);
        ac2 += lo16(wv.w) * rlane(h1v, bl + 6);
        ac3 += hi16(wv.w) * rlane(h1v, bl + 7);
    }
    const float h2v = ftanh((ac0 + ac1) + (ac2 + ac3));

    ac0 = bias3; ac1 = 0.f; ac2 = 0.f; ac3 = 0.f;
#pragma unroll
    for (int k8 = 0; k8 < 8; ++k8) {
        const uint4 wv = W3v[k8 * 16 + jj];
        const int bl = k8 * 8;
        ac0 += lo16(wv.x) * rlane(h2v, bl + 0);
        ac1 += hi16(wv.x) * rlane(h2v, bl + 1);
        ac2 += lo16(wv.y) * rlane(h2v, bl + 2);
        ac3 += hi16(wv.y) * rlane(h2v, bl + 3);
        ac0 += lo16(wv.z) * rlane(h2v, bl + 4);
        ac1 += hi16(wv.z) * rlane(h2v, bl + 5);
        ac2 += lo16(wv.w) * rlane(h2v, bl + 6);
        ac3 += hi16(wv.w) * rlane(h2v, bl + 7);
    }
    const float l3 = (ac0 + ac1) + (ac2 + ac3);   // logit jj lives in lane jj

    // ---- in-wave softmax (logit k in lane k, k<15) ----
    {
        float mx = rlane(l3, 0);
#pragma unroll
        for (int k = 1; k < 15; ++k) mx = fmaxf(mx, rlane(l3, k));
        const float ex = __expf(l3 - mx);
        float s = rlane(ex, 0);
#pragma unroll
        for (int k = 1; k < 15; ++k) s += rlane(ex, k);
        const float cval = ex * frcp(s);
        if (lane < 16) coef_s[wid * 16 + lane] = (lane < 15) ? cval : 0.f;
    }

    __syncthreads();   // coeffs visible; weight region now dead -> tmv reuse

    // ---- phase 3: tm[m][r][e] = sum_k coeff[r][k]*basis_m[k][e] (reg basis) ----
    {
        const float cv0 = coef_s[lane];        // rows 0-3: (r,k)=(lane>>4,lane&15)
        const float cv1 = coef_s[64 + lane];   // rows 4-7
        float acc3[4][8];
#pragma unroll
        for (int m = 0; m < 4; ++m)
#pragma unroll
            for (int r = 0; r < 8; ++r) acc3[m][r] = 0.f;

#pragma unroll
        for (int k = 0; k < 15; ++k) {
            float c[8];
#pragma unroll
            for (int r = 0; r < 4; ++r) {
                c[r]     = rlane(cv0, r * 16 + k);
                c[4 + r] = rlane(cv1, r * 16 + k);
            }
#pragma unroll
            for (int m = 0; m < 4; ++m) {
                const float b = basf[m * 15 + k];
#pragma unroll
                for (int r = 0; r < 8; ++r)
                    acc3[m][r] += c[r] * b;
            }
        }
        if (tid < 436) {
#pragma unroll
            for (int m = 0; m < 4; ++m)
#pragma unroll
                for (int r = 0; r < 8; ++r)
                    tmv[(m * 8 + r) * 436 + tid] = tobf(acc3[m][r]);
        }
    }

    __syncthreads();   // tm visible

    // ---- phase 4: banded mat-vec combos (wave=row, lane i=output dim) ----
    {
        const int i   = lane;
        const int jlo = (i - 3 > 0) ? (i - 3) : 0;
        const int ne  = ((i + 3 < 63) ? (i + 3) : 63) - jlo + 1;
        const int base = (i < 4)  ? (i * (i + 7)) / 2
                       : (i <= 61) ? (7 * i - 6)
                       : (i == 62) ? 427 : 432;

        float nmu = 0.f, nml = 0.f, ncu = 0.f, ncl = 0.f, ncs = 0.f;
#pragma unroll
        for (int d = 0; d < 7; ++d) {
            if (d < ne) {
                const int j  = jlo + d;
                const int eI = base + d;
                float t11 = frombf(tmv[(0 * 8 + wid) * 436 + eI]);
                float t12 = frombf(tmv[(1 * 8 + wid) * 436 + eI]);
                float t21 = frombf(tmv[(2 * 8 + wid) * 436 + eI]);
                float t22 = frombf(tmv[(3 * 8 + wid) * 436 + eI]);
                if (j == i) { t11 += 1.f; t22 += 1.f; }
                const float mu  = pm_s[wid * 128 + j];
                const float ml  = pm_s[wid * 128 + 64 + j];
                const float vcu = pcu_s[wid * 64 + j];
                const float vcl = pcl_s[wid * 64 + j];
                const float vcs = pcs_s[wid * 64 + j];
                nmu += t11 * mu + t12 * ml;
                nml += t21 * mu + t22 * ml;
                ncu += t11 * t11 * vcu + 2.f * t11 * t12 * vcs + t12 * t12 * vcl;
                ncl += t21 * t21 * vcu + 2.f * t21 * t22 * vcs + t22 * t22 * vcl;
                ncs += t21 * t11 * vcu + (t22 * t11 + t21 * t12) * vcs + t22 * t12 * vcl;
            }
        }
        out[O_NM  + row * 128 + i]      = nmu;
        out[O_NM  + row * 128 + 64 + i] = nml;
        out[O_NCU + row * 64 + i] = ncu + tcu;
        out[O_NCL + row * 64 + i] = ncl + tcl;
        out[O_NCS + row * 64 + i] = ncs;
    }
}

extern "C" void kernel_launch(void* const* d_in, const int* in_sizes, int n_in,
                              void* d_out, int out_size, void* d_ws, size_t ws_size,
                              hipStream_t stream) {
    rkn_kernel<<<dim3(512), dim3(512), 0, stream>>>(
        (const float*)d_in[0],  // prior_mean
        (const float*)d_in[1],  // cov_u
        (const float*)d_in[2],  // cov_l
        (const float*)d_in[3],  // cov_s
        (const float*)d_in[4],  // obs
        (const float*)d_in[5],  // obs_var
        (const float*)d_in[6],  // W1
        (const float*)d_in[7],  // b1
        (const float*)d_in[8],  // W2
        (const float*)d_in[9],  // b2
        (const float*)d_in[10], // W3
        (const float*)d_in[11], // b3
        (const float*)d_in[12], // tm11_basis
        (const float*)d_in[13], // tm12_basis
        (const float*)d_in[14], // tm21_basis
        (const float*)d_in[15], // tm22_basis
        (const float*)d_in[16], // log_trans_noise
        (float*)d_out);
}